// Round 1
// baseline (537.996 us; speedup 1.0000x reference)
//
#include <hip/hip_runtime.h>
#include <math.h>

#define NROWS 10000
#define FEAT  512
#define NHID  64
#define NCLS  10
#define YT_STRIDE 10016   // 10000 padded to multiple of 32 (zeros in pad)

typedef __attribute__((ext_vector_type(8))) short short8;
typedef __attribute__((ext_vector_type(4))) float f32x4;

// f32 -> bf16, round-to-nearest-even
__device__ __forceinline__ short f2bf(float f) {
  union { float f; unsigned u; } v; v.f = f;
  unsigned r = v.u + 0x7fffu + ((v.u >> 16) & 1u);
  return (short)(r >> 16);
}

__device__ __forceinline__ float wsum64(float v) {
#pragma unroll
  for (int off = 32; off > 0; off >>= 1) v += __shfl_xor(v, off, 64);
  return v;
}

// ---------------------------------------------------------------------------
// Kernel 0: W [512][64] f32 -> Wt [64][512] bf16 (both branches)
__global__ __launch_bounds__(256) void prep_w(const float* __restrict__ W1,
                                              const float* __restrict__ W2,
                                              unsigned short* __restrict__ Wt1,
                                              unsigned short* __restrict__ Wt2) {
  int i = blockIdx.x * 256 + threadIdx.x;
  if (i >= FEAT * NHID) return;
  int k = i >> 6, h = i & 63;
  Wt1[h * FEAT + k] = (unsigned short)f2bf(W1[i]);
  Wt2[h * FEAT + k] = (unsigned short)f2bf(W2[i]);
}

// ---------------------------------------------------------------------------
// Kernel 1: Yt[col][row] = bf16( (x @ W)[row][col] ).  One wave = 16 rows.
// A: x f32 (cvt to bf16 in regs), B: Wt bf16 [64][512].
__global__ __launch_bounds__(256) void gemm_xw(const float* __restrict__ x,
                                               const unsigned short* __restrict__ Wt1,
                                               const unsigned short* __restrict__ Wt2,
                                               unsigned short* __restrict__ Yt1,
                                               unsigned short* __restrict__ Yt2) {
  const int br = blockIdx.y;
  const unsigned short* Wt = br ? Wt2 : Wt1;
  unsigned short* Yt       = br ? Yt2 : Yt1;

  const int lane = threadIdx.x & 63;
  const int wave = threadIdx.x >> 6;
  const int rowbase = blockIdx.x * 64 + wave * 16;
  if (rowbase >= NROWS) return;
  const int r = lane & 15;   // A row / B col within tile
  const int g = lane >> 4;   // k-group (8 contiguous k each)
  const int ga = g * 8;

  const float* arow = x + (size_t)(rowbase + r) * FEAT + ga;
  const unsigned short* bp[4];
#pragma unroll
  for (int t = 0; t < 4; ++t) bp[t] = Wt + (size_t)(t * 16 + r) * FEAT + ga;

  f32x4 acc[4];
#pragma unroll
  for (int t = 0; t < 4; ++t) acc[t] = (f32x4){0.f, 0.f, 0.f, 0.f};

#pragma unroll 4
  for (int kb = 0; kb < FEAT / 32; ++kb) {
    const int k0 = kb * 32;
    const f32x4* ap = (const f32x4*)(arow + k0);
    f32x4 a0 = ap[0], a1 = ap[1];
    short8 af;
    af[0] = f2bf(a0[0]); af[1] = f2bf(a0[1]); af[2] = f2bf(a0[2]); af[3] = f2bf(a0[3]);
    af[4] = f2bf(a1[0]); af[5] = f2bf(a1[1]); af[6] = f2bf(a1[2]); af[7] = f2bf(a1[3]);
#pragma unroll
    for (int t = 0; t < 4; ++t) {
      short8 bf = *(const short8*)(bp[t] + k0);
      acc[t] = __builtin_amdgcn_mfma_f32_16x16x32_bf16(af, bf, acc[t], 0, 0, 0);
    }
  }
  // C layout: col = lane&15, row = (lane>>4)*4 + reg   -> scatter to Yt[col][row]
#pragma unroll
  for (int t = 0; t < 4; ++t)
#pragma unroll
    for (int rr = 0; rr < 4; ++rr)
      Yt[(size_t)(t * 16 + r) * YT_STRIDE + (rowbase + g * 4 + rr)] =
          (unsigned short)f2bf(acc[t][rr]);
}

// ---------------------------------------------------------------------------
// Kernel 2 (the hot one): E = adj @ Y.  adj f32 streamed from HBM, cvt bf16 in
// regs; B from Yt (bf16, transposed, zero-padded to 10016).  One wave = 16 rows
// x 64 cols, K loop = 313 steps of 32 (tail covered by Yt zero-pad + A clamp).
// No LDS, no barriers.
__global__ __launch_bounds__(256) void gemm_adj(const float* __restrict__ adj1,
                                                const float* __restrict__ adj2,
                                                const unsigned short* __restrict__ Yt1,
                                                const unsigned short* __restrict__ Yt2,
                                                float* __restrict__ E1,
                                                float* __restrict__ E2) {
  const int br = blockIdx.y;
  const float* adj          = br ? adj2 : adj1;
  const unsigned short* Yt  = br ? Yt2 : Yt1;
  float* E                  = br ? E2 : E1;

  const int lane = threadIdx.x & 63;
  const int wave = threadIdx.x >> 6;
  const int rowbase = blockIdx.x * 64 + wave * 16;
  if (rowbase >= NROWS) return;
  const int r = lane & 15;
  const int g = lane >> 4;
  const int ga = g * 8;

  const float* arow = adj + (size_t)(rowbase + r) * NROWS;
  const unsigned short* b0 = Yt + (size_t)(0 * 16 + r) * YT_STRIDE + ga;
  const unsigned short* b1 = Yt + (size_t)(1 * 16 + r) * YT_STRIDE + ga;
  const unsigned short* b2 = Yt + (size_t)(2 * 16 + r) * YT_STRIDE + ga;
  const unsigned short* b3 = Yt + (size_t)(3 * 16 + r) * YT_STRIDE + ga;

  f32x4 acc0 = (f32x4){0.f, 0.f, 0.f, 0.f};
  f32x4 acc1 = acc0, acc2 = acc0, acc3 = acc0;

#pragma unroll 4
  for (int kb = 0; kb < 313; ++kb) {
    const int k0 = kb * 32;
    const int kc = min(k0 + ga, 9992);  // keep 8-float read inside the row
    const f32x4* ap = (const f32x4*)(arow + kc);
    f32x4 a0 = ap[0], a1 = ap[1];
    short8 af;
    af[0] = f2bf(a0[0]); af[1] = f2bf(a0[1]); af[2] = f2bf(a0[2]); af[3] = f2bf(a0[3]);
    af[4] = f2bf(a1[0]); af[5] = f2bf(a1[1]); af[6] = f2bf(a1[2]); af[7] = f2bf(a1[3]);
    short8 bf0 = *(const short8*)(b0 + k0);
    short8 bf1 = *(const short8*)(b1 + k0);
    short8 bf2 = *(const short8*)(b2 + k0);
    short8 bf3 = *(const short8*)(b3 + k0);
    acc0 = __builtin_amdgcn_mfma_f32_16x16x32_bf16(af, bf0, acc0, 0, 0, 0);
    acc1 = __builtin_amdgcn_mfma_f32_16x16x32_bf16(af, bf1, acc1, 0, 0, 0);
    acc2 = __builtin_amdgcn_mfma_f32_16x16x32_bf16(af, bf2, acc2, 0, 0, 0);
    acc3 = __builtin_amdgcn_mfma_f32_16x16x32_bf16(af, bf3, acc3, 0, 0, 0);
  }

  const size_t ebase = (size_t)(rowbase + g * 4) * NHID + r;
#pragma unroll
  for (int rr = 0; rr < 4; ++rr) {
    E[ebase + (size_t)rr * NHID +  0] = acc0[rr];
    E[ebase + (size_t)rr * NHID + 16] = acc1[rr];
    E[ebase + (size_t)rr * NHID + 32] = acc2[rr];
    E[ebase + (size_t)rr * NHID + 48] = acc3[rr];
  }
}

// ---------------------------------------------------------------------------
// Kernel 3: bias + 2-way attention softmax fusion + DEC assignment.
// One wave per row (lane = h).
__global__ __launch_bounds__(256) void fuse(const float* __restrict__ E1,
                                            const float* __restrict__ E2,
                                            const float* __restrict__ b1,
                                            const float* __restrict__ b2,
                                            const float* __restrict__ aw,
                                            const float* __restrict__ cl,
                                            float* __restrict__ out) {
  const int lane = threadIdx.x & 63;
  const int wave = threadIdx.x >> 6;
  const int row = blockIdx.x * 4 + wave;
  if (row >= NROWS) return;

  float e1 = E1[(size_t)row * NHID + lane] + b1[lane];
  float e2 = E2[(size_t)row * NHID + lane] + b2[lane];
  float a = aw[lane];
  float w1 = wsum64(e1 * a);
  float w2 = wsum64(e2 * a);
  float m = fmaxf(w1, w2);
  float x1 = __expf(w1 - m), x2 = __expf(w2 - m);
  // use precise expf to stay close to reference
  x1 = expf(w1 - m); x2 = expf(w2 - m);
  float inv = 1.0f / (x1 + x2);
  float be1 = x1 * inv, be2 = x2 * inv;
  float emb = be1 * e1 + be2 * e2;
  out[(size_t)row * NHID + lane] = emb;

  float myq = 0.f, qs = 0.f;
#pragma unroll
  for (int c = 0; c < NCLS; ++c) {
    float d = emb - cl[c * NHID + lane];
    float s = wsum64(d * d);
    float t = 1.0f / (1.0f + s * 5.0f);   // d2 / ALPHA, ALPHA=0.2
    t = powf(t, 0.6f);                    // ** ((ALPHA+1)/2)
    t = powf(t, 1.2f) * 0.5f;             // ** (ALPHA+1) / 2
    qs += t;
    if (lane == c) myq = t;
  }
  if (lane < NCLS) out[(size_t)NROWS * NHID + (size_t)row * NCLS + lane] = myq / qs;
}

// ---------------------------------------------------------------------------
extern "C" void kernel_launch(void* const* d_in, const int* in_sizes, int n_in,
                              void* d_out, int out_size, void* d_ws, size_t ws_size,
                              hipStream_t stream) {
  const float* x    = (const float*)d_in[0];
  const float* adj1 = (const float*)d_in[1];
  const float* adj2 = (const float*)d_in[2];
  const float* W1   = (const float*)d_in[3];
  const float* b1   = (const float*)d_in[4];
  const float* W2   = (const float*)d_in[5];
  const float* b2   = (const float*)d_in[6];
  const float* aw   = (const float*)d_in[7];
  const float* cl   = (const float*)d_in[8];
  float* out = (float*)d_out;

  // workspace layout (all offsets 256B-aligned)
  char* ws = (char*)d_ws;
  unsigned short* Yt1 = (unsigned short*)(ws + 0);        // 64*10016*2 = 1282048
  unsigned short* Yt2 = (unsigned short*)(ws + 1282048);
  unsigned short* Wt1 = (unsigned short*)(ws + 2564096);  // 64*512*2 = 65536
  unsigned short* Wt2 = (unsigned short*)(ws + 2629632);
  float* E1           = (float*)(ws + 2695168);           // 10000*64*4 = 2560000
  float* E2           = (float*)(ws + 5255168);           // end 7815168

  // zero Yt (covers the K-tail zero pad rows 10000..10015)
  hipMemsetAsync(Yt1, 0, 2 * 1282048, stream);
  prep_w<<<dim3(128), dim3(256), 0, stream>>>(W1, W2, Wt1, Wt2);
  gemm_xw<<<dim3(157, 2), dim3(256), 0, stream>>>(x, Wt1, Wt2, Yt1, Yt2);
  gemm_adj<<<dim3(157, 2), dim3(256), 0, stream>>>(adj1, adj2, Yt1, Yt2, E1, E2);
  fuse<<<dim3(2500), dim3(256), 0, stream>>>(E1, E2, b1, b2, aw, cl, out);
}

// Round 2
// 385.060 us; speedup vs baseline: 1.3972x; 1.3972x over previous
//
#include <hip/hip_runtime.h>
#include <math.h>

#define NROWS 10000
#define FEAT  512
#define NHID  64
#define NCLS  10
#define YT_STRIDE 10016   // 10000 padded to multiple of 32 (zeros in pad)
#define KB_TOTAL 313      // ceil(10000/32)

typedef __attribute__((ext_vector_type(8))) short short8;
typedef __attribute__((ext_vector_type(4))) float f32x4;

// f32 -> bf16, round-to-nearest-even
__device__ __forceinline__ short f2bf(float f) {
  union { float f; unsigned u; } v; v.f = f;
  unsigned r = v.u + 0x7fffu + ((v.u >> 16) & 1u);
  return (short)(r >> 16);
}

__device__ __forceinline__ float wsum64(float v) {
#pragma unroll
  for (int off = 32; off > 0; off >>= 1) v += __shfl_xor(v, off, 64);
  return v;
}

// ---------------------------------------------------------------------------
// Kernel 0: W [512][64] f32 -> Wt [64][512] bf16 (both branches)
__global__ __launch_bounds__(256) void prep_w(const float* __restrict__ W1,
                                              const float* __restrict__ W2,
                                              unsigned short* __restrict__ Wt1,
                                              unsigned short* __restrict__ Wt2) {
  int i = blockIdx.x * 256 + threadIdx.x;
  if (i >= FEAT * NHID) return;
  int k = i >> 6, h = i & 63;
  Wt1[h * FEAT + k] = (unsigned short)f2bf(W1[i]);
  Wt2[h * FEAT + k] = (unsigned short)f2bf(W2[i]);
}

// ---------------------------------------------------------------------------
// Kernel 1: both branches in one pass (x read once).
// Yt_b[col][row] = bf16( (x @ W_b)[row][col] ).  One wave = 16 rows.
__global__ __launch_bounds__(256) void gemm_xw(const float* __restrict__ x,
                                               const unsigned short* __restrict__ Wt1,
                                               const unsigned short* __restrict__ Wt2,
                                               unsigned short* __restrict__ Yt1,
                                               unsigned short* __restrict__ Yt2) {
  const int lane = threadIdx.x & 63;
  const int wave = threadIdx.x >> 6;
  const int rowbase = blockIdx.x * 64 + wave * 16;
  if (rowbase >= NROWS) return;
  const int r = lane & 15;   // A row / B col within tile
  const int g = lane >> 4;   // k-group (8 contiguous k each)
  const int ga = g * 8;

  const float* arow = x + (size_t)(rowbase + r) * FEAT + ga;
  const unsigned short* bp1[4];
  const unsigned short* bp2[4];
#pragma unroll
  for (int t = 0; t < 4; ++t) {
    bp1[t] = Wt1 + (size_t)(t * 16 + r) * FEAT + ga;
    bp2[t] = Wt2 + (size_t)(t * 16 + r) * FEAT + ga;
  }

  f32x4 acc1[4], acc2[4];
#pragma unroll
  for (int t = 0; t < 4; ++t) {
    acc1[t] = (f32x4){0.f, 0.f, 0.f, 0.f};
    acc2[t] = (f32x4){0.f, 0.f, 0.f, 0.f};
  }

#pragma unroll 8
  for (int kb = 0; kb < FEAT / 32; ++kb) {
    const int k0 = kb * 32;
    const f32x4* ap = (const f32x4*)(arow + k0);
    f32x4 a0 = ap[0], a1 = ap[1];
    short8 af;
    af[0] = f2bf(a0[0]); af[1] = f2bf(a0[1]); af[2] = f2bf(a0[2]); af[3] = f2bf(a0[3]);
    af[4] = f2bf(a1[0]); af[5] = f2bf(a1[1]); af[6] = f2bf(a1[2]); af[7] = f2bf(a1[3]);
#pragma unroll
    for (int t = 0; t < 4; ++t) {
      short8 bf1 = *(const short8*)(bp1[t] + k0);
      acc1[t] = __builtin_amdgcn_mfma_f32_16x16x32_bf16(af, bf1, acc1[t], 0, 0, 0);
      short8 bf2 = *(const short8*)(bp2[t] + k0);
      acc2[t] = __builtin_amdgcn_mfma_f32_16x16x32_bf16(af, bf2, acc2[t], 0, 0, 0);
    }
  }
  // C layout: col = lane&15, row = (lane>>4)*4 + reg   -> scatter to Yt[col][row]
#pragma unroll
  for (int t = 0; t < 4; ++t)
#pragma unroll
    for (int rr = 0; rr < 4; ++rr) {
      Yt1[(size_t)(t * 16 + r) * YT_STRIDE + (rowbase + g * 4 + rr)] =
          (unsigned short)f2bf(acc1[t][rr]);
      Yt2[(size_t)(t * 16 + r) * YT_STRIDE + (rowbase + g * 4 + rr)] =
          (unsigned short)f2bf(acc2[t][rr]);
    }
}

// ---------------------------------------------------------------------------
// Kernel 2 (the hot one): E = adj @ Y with split-K.
// grid (157, 2 branches, NSPLIT).  Each split writes a private partial
// Ep[branch][split][N][64] (bitwise-deterministic; no atomics).
__global__ __launch_bounds__(256) void gemm_adj(const float* __restrict__ adj1,
                                                const float* __restrict__ adj2,
                                                const unsigned short* __restrict__ Yt1,
                                                const unsigned short* __restrict__ Yt2,
                                                float* __restrict__ Ep,
                                                int nsplit, int chunk) {
  const int br = blockIdx.y;
  const int sp = blockIdx.z;
  const float* adj          = br ? adj2 : adj1;
  const unsigned short* Yt  = br ? Yt2 : Yt1;
  float* E = Ep + (size_t)(br * nsplit + sp) * NROWS * NHID;

  const int kb_begin = sp * chunk;
  const int kb_end   = min(kb_begin + chunk, KB_TOTAL);

  const int lane = threadIdx.x & 63;
  const int wave = threadIdx.x >> 6;
  const int rowbase = blockIdx.x * 64 + wave * 16;
  if (rowbase >= NROWS) return;
  const int r = lane & 15;
  const int g = lane >> 4;
  const int ga = g * 8;

  const float* arow = adj + (size_t)(rowbase + r) * NROWS;
  const unsigned short* b0 = Yt + (size_t)(0 * 16 + r) * YT_STRIDE + ga;
  const unsigned short* b1 = Yt + (size_t)(1 * 16 + r) * YT_STRIDE + ga;
  const unsigned short* b2 = Yt + (size_t)(2 * 16 + r) * YT_STRIDE + ga;
  const unsigned short* b3 = Yt + (size_t)(3 * 16 + r) * YT_STRIDE + ga;

  f32x4 acc0 = (f32x4){0.f, 0.f, 0.f, 0.f};
  f32x4 acc1 = acc0, acc2 = acc0, acc3 = acc0;

#pragma unroll 4
  for (int kb = kb_begin; kb < kb_end; ++kb) {
    const int k0 = kb * 32;
    const int kc = min(k0 + ga, 9992);  // keep 8-float read inside the row
    const f32x4* ap = (const f32x4*)(arow + kc);
    f32x4 a0 = ap[0], a1 = ap[1];
    short8 af;
    af[0] = f2bf(a0[0]); af[1] = f2bf(a0[1]); af[2] = f2bf(a0[2]); af[3] = f2bf(a0[3]);
    af[4] = f2bf(a1[0]); af[5] = f2bf(a1[1]); af[6] = f2bf(a1[2]); af[7] = f2bf(a1[3]);
    short8 bf0 = *(const short8*)(b0 + k0);
    short8 bf1 = *(const short8*)(b1 + k0);
    short8 bf2 = *(const short8*)(b2 + k0);
    short8 bf3 = *(const short8*)(b3 + k0);
    acc0 = __builtin_amdgcn_mfma_f32_16x16x32_bf16(af, bf0, acc0, 0, 0, 0);
    acc1 = __builtin_amdgcn_mfma_f32_16x16x32_bf16(af, bf1, acc1, 0, 0, 0);
    acc2 = __builtin_amdgcn_mfma_f32_16x16x32_bf16(af, bf2, acc2, 0, 0, 0);
    acc3 = __builtin_amdgcn_mfma_f32_16x16x32_bf16(af, bf3, acc3, 0, 0, 0);
  }

  const size_t ebase = (size_t)(rowbase + g * 4) * NHID + r;
#pragma unroll
  for (int rr = 0; rr < 4; ++rr) {
    E[ebase + (size_t)rr * NHID +  0] = acc0[rr];
    E[ebase + (size_t)rr * NHID + 16] = acc1[rr];
    E[ebase + (size_t)rr * NHID + 32] = acc2[rr];
    E[ebase + (size_t)rr * NHID + 48] = acc3[rr];
  }
}

// ---------------------------------------------------------------------------
// Kernel 3: split-K reduction + bias + 2-way attention fusion + DEC assignment.
// One wave per row (lane = h).
__global__ __launch_bounds__(256) void fuse(const float* __restrict__ Ep,
                                            int nsplit,
                                            const float* __restrict__ b1,
                                            const float* __restrict__ b2,
                                            const float* __restrict__ aw,
                                            const float* __restrict__ cl,
                                            float* __restrict__ out) {
  const int lane = threadIdx.x & 63;
  const int wave = threadIdx.x >> 6;
  const int row = blockIdx.x * 4 + wave;
  if (row >= NROWS) return;

  const size_t off = (size_t)row * NHID + lane;
  const size_t bstride = (size_t)nsplit * NROWS * NHID;
  float e1 = b1[lane], e2 = b2[lane];
  for (int s = 0; s < nsplit; ++s) {
    e1 += Ep[(size_t)s * NROWS * NHID + off];
    e2 += Ep[bstride + (size_t)s * NROWS * NHID + off];
  }

  float a = aw[lane];
  float w1 = wsum64(e1 * a);
  float w2 = wsum64(e2 * a);
  float m = fmaxf(w1, w2);
  float x1 = expf(w1 - m), x2 = expf(w2 - m);
  float inv = 1.0f / (x1 + x2);
  float emb = (x1 * e1 + x2 * e2) * inv;
  out[off] = emb;

  float myq = 0.f, qs = 0.f;
#pragma unroll
  for (int c = 0; c < NCLS; ++c) {
    float d = emb - cl[c * NHID + lane];
    float s = wsum64(d * d);
    float t = 1.0f / (1.0f + s * 5.0f);   // d2 / ALPHA, ALPHA=0.2
    t = powf(t, 0.6f);                    // ** ((ALPHA+1)/2)
    t = powf(t, 1.2f) * 0.5f;             // ** (ALPHA+1) / 2
    qs += t;
    if (lane == c) myq = t;
  }
  if (lane < NCLS) out[(size_t)NROWS * NHID + (size_t)row * NCLS + lane] = myq / qs;
}

// ---------------------------------------------------------------------------
extern "C" void kernel_launch(void* const* d_in, const int* in_sizes, int n_in,
                              void* d_out, int out_size, void* d_ws, size_t ws_size,
                              hipStream_t stream) {
  const float* x    = (const float*)d_in[0];
  const float* adj1 = (const float*)d_in[1];
  const float* adj2 = (const float*)d_in[2];
  const float* W1   = (const float*)d_in[3];
  const float* b1   = (const float*)d_in[4];
  const float* W2   = (const float*)d_in[5];
  const float* b2   = (const float*)d_in[6];
  const float* aw   = (const float*)d_in[7];
  const float* cl   = (const float*)d_in[8];
  float* out = (float*)d_out;

  // workspace layout (all offsets 256B-aligned)
  char* ws = (char*)d_ws;
  unsigned short* Yt1 = (unsigned short*)(ws + 0);        // 64*10016*2 = 1282048
  unsigned short* Yt2 = (unsigned short*)(ws + 1282048);
  unsigned short* Wt1 = (unsigned short*)(ws + 2564096);  // 64*512*2 = 65536
  unsigned short* Wt2 = (unsigned short*)(ws + 2629632);
  float* Ep           = (float*)(ws + 2695168);           // partials start here

  // pick split-K so partials fit the workspace (deterministic: depends only
  // on ws_size, which is fixed for the session)
  const size_t fixed = 2695168;
  const size_t per_split = 2ull * NROWS * NHID * 4ull;    // both branches
  int nsplit = 1;
  if (ws_size > fixed + per_split) {
    size_t s = (ws_size - fixed) / per_split;
    nsplit = (int)(s < 8 ? s : 8);
    if (nsplit < 1) nsplit = 1;
  }
  const int chunk = (KB_TOTAL + nsplit - 1) / nsplit;

  // zero Yt (covers the K-tail zero pad rows 10000..10015)
  hipMemsetAsync(Yt1, 0, 2 * 1282048, stream);
  prep_w<<<dim3(128), dim3(256), 0, stream>>>(W1, W2, Wt1, Wt2);
  gemm_xw<<<dim3(157), dim3(256), 0, stream>>>(x, Wt1, Wt2, Yt1, Yt2);
  gemm_adj<<<dim3(157, 2, nsplit), dim3(256), 0, stream>>>(adj1, adj2, Yt1, Yt2,
                                                           Ep, nsplit, chunk);
  fuse<<<dim3(2500), dim3(256), 0, stream>>>(Ep, nsplit, b1, b2, aw, cl, out);
}

// Round 3
// 367.288 us; speedup vs baseline: 1.4648x; 1.0484x over previous
//
#include <hip/hip_runtime.h>
#include <math.h>

#define NROWS 10000
#define FEAT  512
#define NHID  64
#define NCLS  10
#define YT_STRIDE 10240   // 10000 padded to multiple of 32*PF (zeros in pad)
#define KB_PAD 320        // padded K blocks of 32
#define NSPLIT 8
#define CHUNK 40          // KB_PAD / NSPLIT

typedef __attribute__((ext_vector_type(8))) short short8;
typedef __attribute__((ext_vector_type(4))) float f32x4;

// f32 -> bf16, round-to-nearest-even
__device__ __forceinline__ short f2bf(float f) {
  union { float f; unsigned u; } v; v.f = f;
  unsigned r = v.u + 0x7fffu + ((v.u >> 16) & 1u);
  return (short)(r >> 16);
}

__device__ __forceinline__ float wsum64(float v) {
#pragma unroll
  for (int off = 32; off > 0; off >>= 1) v += __shfl_xor(v, off, 64);
  return v;
}

// ---------------------------------------------------------------------------
// Kernel 0: W [512][64] f32 -> Wt [64][512] bf16 (both branches)
__global__ __launch_bounds__(256) void prep_w(const float* __restrict__ W1,
                                              const float* __restrict__ W2,
                                              unsigned short* __restrict__ Wt1,
                                              unsigned short* __restrict__ Wt2) {
  int i = blockIdx.x * 256 + threadIdx.x;
  if (i >= FEAT * NHID) return;
  int k = i >> 6, h = i & 63;
  Wt1[h * FEAT + k] = (unsigned short)f2bf(W1[i]);
  Wt2[h * FEAT + k] = (unsigned short)f2bf(W2[i]);
}

// ---------------------------------------------------------------------------
// Kernel 1: both branches in one pass (x read once), PF-2 software pipeline.
// Yt_b[col][row] = bf16( (x @ W_b)[row][col] ).  One wave = 16 rows.
__global__ __launch_bounds__(256, 3) void gemm_xw(const float* __restrict__ x,
                                                  const unsigned short* __restrict__ Wt1,
                                                  const unsigned short* __restrict__ Wt2,
                                                  unsigned short* __restrict__ Yt1,
                                                  unsigned short* __restrict__ Yt2) {
  const int lane = threadIdx.x & 63;
  const int wave = threadIdx.x >> 6;
  const int rowbase = blockIdx.x * 64 + wave * 16;
  if (rowbase >= NROWS) return;
  const int r = lane & 15;   // A row / B col within tile
  const int g = lane >> 4;   // k-group (8 contiguous k each)
  const int ga = g * 8;

  const float* arow = x + (size_t)(rowbase + r) * FEAT + ga;
  const size_t woff = (size_t)r * FEAT + ga;

  f32x4 Ax[2][2];
  short8 Bx[2][8];
  f32x4 acc1[4], acc2[4];
#pragma unroll
  for (int t = 0; t < 4; ++t) {
    acc1[t] = (f32x4){0.f, 0.f, 0.f, 0.f};
    acc2[t] = (f32x4){0.f, 0.f, 0.f, 0.f};
  }

#define LOADX(s, it) { const int k0 = (it) * 32;                                 \
    const f32x4* ap = (const f32x4*)(arow + k0);                                 \
    Ax[s][0] = ap[0]; Ax[s][1] = ap[1];                                          \
    Bx[s][0] = *(const short8*)(Wt1 + woff + k0);                                \
    Bx[s][1] = *(const short8*)(Wt1 + woff + 8192 + k0);                         \
    Bx[s][2] = *(const short8*)(Wt1 + woff + 16384 + k0);                        \
    Bx[s][3] = *(const short8*)(Wt1 + woff + 24576 + k0);                        \
    Bx[s][4] = *(const short8*)(Wt2 + woff + k0);                                \
    Bx[s][5] = *(const short8*)(Wt2 + woff + 8192 + k0);                         \
    Bx[s][6] = *(const short8*)(Wt2 + woff + 16384 + k0);                        \
    Bx[s][7] = *(const short8*)(Wt2 + woff + 24576 + k0); }

#define COMPX(s) { short8 af;                                                    \
    af[0] = f2bf(Ax[s][0][0]); af[1] = f2bf(Ax[s][0][1]);                        \
    af[2] = f2bf(Ax[s][0][2]); af[3] = f2bf(Ax[s][0][3]);                        \
    af[4] = f2bf(Ax[s][1][0]); af[5] = f2bf(Ax[s][1][1]);                        \
    af[6] = f2bf(Ax[s][1][2]); af[7] = f2bf(Ax[s][1][3]);                        \
    acc1[0] = __builtin_amdgcn_mfma_f32_16x16x32_bf16(af, Bx[s][0], acc1[0], 0, 0, 0); \
    acc1[1] = __builtin_amdgcn_mfma_f32_16x16x32_bf16(af, Bx[s][1], acc1[1], 0, 0, 0); \
    acc1[2] = __builtin_amdgcn_mfma_f32_16x16x32_bf16(af, Bx[s][2], acc1[2], 0, 0, 0); \
    acc1[3] = __builtin_amdgcn_mfma_f32_16x16x32_bf16(af, Bx[s][3], acc1[3], 0, 0, 0); \
    acc2[0] = __builtin_amdgcn_mfma_f32_16x16x32_bf16(af, Bx[s][4], acc2[0], 0, 0, 0); \
    acc2[1] = __builtin_amdgcn_mfma_f32_16x16x32_bf16(af, Bx[s][5], acc2[1], 0, 0, 0); \
    acc2[2] = __builtin_amdgcn_mfma_f32_16x16x32_bf16(af, Bx[s][6], acc2[2], 0, 0, 0); \
    acc2[3] = __builtin_amdgcn_mfma_f32_16x16x32_bf16(af, Bx[s][7], acc2[3], 0, 0, 0); }

  LOADX(0, 0) LOADX(1, 1)
#pragma unroll 1
  for (int i = 0; i < 14; i += 2) {
    COMPX(0) LOADX(0, i + 2)
    COMPX(1) LOADX(1, i + 3)
  }
  COMPX(0) COMPX(1)
#undef LOADX
#undef COMPX

  // C layout: col = lane&15, row = (lane>>4)*4 + reg   -> scatter to Yt[col][row]
#pragma unroll
  for (int t = 0; t < 4; ++t)
#pragma unroll
    for (int rr = 0; rr < 4; ++rr) {
      Yt1[(size_t)(t * 16 + r) * YT_STRIDE + (rowbase + g * 4 + rr)] =
          (unsigned short)f2bf(acc1[t][rr]);
      Yt2[(size_t)(t * 16 + r) * YT_STRIDE + (rowbase + g * 4 + rr)] =
          (unsigned short)f2bf(acc2[t][rr]);
    }
}

// ---------------------------------------------------------------------------
// Kernel 2 (the hot one): E = adj @ Y with static split-K and an explicit
// depth-4 software pipeline (24 loads in flight per wave).  grid (157, split,
// branch) so branch-0 blocks drain before branch-1 (one Yt per XCD L2 at a
// time).  Each split writes a private partial Ep[branch][split][N][64].
__global__ __launch_bounds__(256, 3) void gemm_adj(const float* __restrict__ adj1,
                                                   const float* __restrict__ adj2,
                                                   const unsigned short* __restrict__ Yt1,
                                                   const unsigned short* __restrict__ Yt2,
                                                   float* __restrict__ Ep) {
  const int sp = blockIdx.y;
  const int br = blockIdx.z;
  const float* adj          = br ? adj2 : adj1;
  const unsigned short* Yt  = br ? Yt2 : Yt1;
  float* E = Ep + (size_t)(br * NSPLIT + sp) * NROWS * NHID;
  const int kb0 = sp * CHUNK;

  const int lane = threadIdx.x & 63;
  const int wave = threadIdx.x >> 6;
  const int rowbase = blockIdx.x * 64 + wave * 16;
  if (rowbase >= NROWS) return;
  const int r = lane & 15;
  const int g = lane >> 4;
  const int ga = g * 8;

  const float* arow = adj + (size_t)(rowbase + r) * NROWS;
  const size_t boff = (size_t)r * YT_STRIDE + ga;

  f32x4 As[4][2];
  short8 Bs[4][4];
  f32x4 acc0 = (f32x4){0.f, 0.f, 0.f, 0.f};
  f32x4 acc1 = acc0, acc2 = acc0, acc3 = acc0;

#define LOADI(s, it) { const int k0 = (kb0 + (it)) * 32;                         \
    const int kc = min(k0 + ga, 9992);                                           \
    const f32x4* ap = (const f32x4*)(arow + kc);                                 \
    As[s][0] = ap[0]; As[s][1] = ap[1];                                          \
    Bs[s][0] = *(const short8*)(Yt + boff + k0);                                 \
    Bs[s][1] = *(const short8*)(Yt + boff + 16 * YT_STRIDE + k0);                \
    Bs[s][2] = *(const short8*)(Yt + boff + 32 * YT_STRIDE + k0);                \
    Bs[s][3] = *(const short8*)(Yt + boff + 48 * YT_STRIDE + k0); }

#define COMPI(s) { short8 af;                                                    \
    af[0] = f2bf(As[s][0][0]); af[1] = f2bf(As[s][0][1]);                        \
    af[2] = f2bf(As[s][0][2]); af[3] = f2bf(As[s][0][3]);                        \
    af[4] = f2bf(As[s][1][0]); af[5] = f2bf(As[s][1][1]);                        \
    af[6] = f2bf(As[s][1][2]); af[7] = f2bf(As[s][1][3]);                        \
    acc0 = __builtin_amdgcn_mfma_f32_16x16x32_bf16(af, Bs[s][0], acc0, 0, 0, 0); \
    acc1 = __builtin_amdgcn_mfma_f32_16x16x32_bf16(af, Bs[s][1], acc1, 0, 0, 0); \
    acc2 = __builtin_amdgcn_mfma_f32_16x16x32_bf16(af, Bs[s][2], acc2, 0, 0, 0); \
    acc3 = __builtin_amdgcn_mfma_f32_16x16x32_bf16(af, Bs[s][3], acc3, 0, 0, 0); }

  LOADI(0, 0) LOADI(1, 1) LOADI(2, 2) LOADI(3, 3)
#pragma unroll 1
  for (int i = 0; i < CHUNK - 4; i += 4) {
    COMPI(0) LOADI(0, i + 4)
    COMPI(1) LOADI(1, i + 5)
    COMPI(2) LOADI(2, i + 6)
    COMPI(3) LOADI(3, i + 7)
  }
  COMPI(0) COMPI(1) COMPI(2) COMPI(3)
#undef LOADI
#undef COMPI

  const size_t ebase = (size_t)(rowbase + g * 4) * NHID + r;
#pragma unroll
  for (int rr = 0; rr < 4; ++rr) {
    E[ebase + (size_t)rr * NHID +  0] = acc0[rr];
    E[ebase + (size_t)rr * NHID + 16] = acc1[rr];
    E[ebase + (size_t)rr * NHID + 32] = acc2[rr];
    E[ebase + (size_t)rr * NHID + 48] = acc3[rr];
  }
}

// ---------------------------------------------------------------------------
// Fallback (dynamic split) if workspace is tight.
__global__ __launch_bounds__(256) void gemm_adj_dyn(const float* __restrict__ adj1,
                                                    const float* __restrict__ adj2,
                                                    const unsigned short* __restrict__ Yt1,
                                                    const unsigned short* __restrict__ Yt2,
                                                    float* __restrict__ Ep,
                                                    int nsplit, int chunk) {
  const int sp = blockIdx.y;
  const int br = blockIdx.z;
  const float* adj          = br ? adj2 : adj1;
  const unsigned short* Yt  = br ? Yt2 : Yt1;
  float* E = Ep + (size_t)(br * nsplit + sp) * NROWS * NHID;

  const int kb_begin = sp * chunk;
  const int kb_end   = min(kb_begin + chunk, KB_PAD);

  const int lane = threadIdx.x & 63;
  const int wave = threadIdx.x >> 6;
  const int rowbase = blockIdx.x * 64 + wave * 16;
  if (rowbase >= NROWS) return;
  const int r = lane & 15;
  const int g = lane >> 4;
  const int ga = g * 8;

  const float* arow = adj + (size_t)(rowbase + r) * NROWS;
  const size_t boff = (size_t)r * YT_STRIDE + ga;

  f32x4 acc0 = (f32x4){0.f, 0.f, 0.f, 0.f};
  f32x4 acc1 = acc0, acc2 = acc0, acc3 = acc0;

#pragma unroll 4
  for (int kb = kb_begin; kb < kb_end; ++kb) {
    const int k0 = kb * 32;
    const int kc = min(k0 + ga, 9992);
    const f32x4* ap = (const f32x4*)(arow + kc);
    f32x4 a0 = ap[0], a1 = ap[1];
    short8 af;
    af[0] = f2bf(a0[0]); af[1] = f2bf(a0[1]); af[2] = f2bf(a0[2]); af[3] = f2bf(a0[3]);
    af[4] = f2bf(a1[0]); af[5] = f2bf(a1[1]); af[6] = f2bf(a1[2]); af[7] = f2bf(a1[3]);
    short8 bf0 = *(const short8*)(Yt + boff + k0);
    short8 bf1 = *(const short8*)(Yt + boff + 16 * YT_STRIDE + k0);
    short8 bf2 = *(const short8*)(Yt + boff + 32 * YT_STRIDE + k0);
    short8 bf3 = *(const short8*)(Yt + boff + 48 * YT_STRIDE + k0);
    acc0 = __builtin_amdgcn_mfma_f32_16x16x32_bf16(af, bf0, acc0, 0, 0, 0);
    acc1 = __builtin_amdgcn_mfma_f32_16x16x32_bf16(af, bf1, acc1, 0, 0, 0);
    acc2 = __builtin_amdgcn_mfma_f32_16x16x32_bf16(af, bf2, acc2, 0, 0, 0);
    acc3 = __builtin_amdgcn_mfma_f32_16x16x32_bf16(af, bf3, acc3, 0, 0, 0);
  }

  const size_t ebase = (size_t)(rowbase + g * 4) * NHID + r;
#pragma unroll
  for (int rr = 0; rr < 4; ++rr) {
    E[ebase + (size_t)rr * NHID +  0] = acc0[rr];
    E[ebase + (size_t)rr * NHID + 16] = acc1[rr];
    E[ebase + (size_t)rr * NHID + 32] = acc2[rr];
    E[ebase + (size_t)rr * NHID + 48] = acc3[rr];
  }
}

// ---------------------------------------------------------------------------
// Kernel 3: split-K reduction + bias + 2-way attention fusion + DEC assignment.
// One wave per row (lane = h).
__global__ __launch_bounds__(256) void fuse(const float* __restrict__ Ep,
                                            int nsplit,
                                            const float* __restrict__ b1,
                                            const float* __restrict__ b2,
                                            const float* __restrict__ aw,
                                            const float* __restrict__ cl,
                                            float* __restrict__ out) {
  const int lane = threadIdx.x & 63;
  const int wave = threadIdx.x >> 6;
  const int row = blockIdx.x * 4 + wave;
  if (row >= NROWS) return;

  const size_t off = (size_t)row * NHID + lane;
  const size_t bstride = (size_t)nsplit * NROWS * NHID;
  float e1 = b1[lane], e2 = b2[lane];
  for (int s = 0; s < nsplit; ++s) {
    e1 += Ep[(size_t)s * NROWS * NHID + off];
    e2 += Ep[bstride + (size_t)s * NROWS * NHID + off];
  }

  float a = aw[lane];
  float w1 = wsum64(e1 * a);
  float w2 = wsum64(e2 * a);
  float m = fmaxf(w1, w2);
  float x1 = expf(w1 - m), x2 = expf(w2 - m);
  float inv = 1.0f / (x1 + x2);
  float emb = (x1 * e1 + x2 * e2) * inv;
  out[off] = emb;

  float myq = 0.f, qs = 0.f;
#pragma unroll
  for (int c = 0; c < NCLS; ++c) {
    float d = emb - cl[c * NHID + lane];
    float s = wsum64(d * d);
    float t = 1.0f / (1.0f + s * 5.0f);   // d2 / ALPHA, ALPHA=0.2
    t = powf(t, 0.6f);                    // ** ((ALPHA+1)/2)
    t = powf(t, 1.2f) * 0.5f;             // ** (ALPHA+1) / 2
    qs += t;
    if (lane == c) myq = t;
  }
  if (lane < NCLS) out[(size_t)NROWS * NHID + (size_t)row * NCLS + lane] = myq / qs;
}

// ---------------------------------------------------------------------------
extern "C" void kernel_launch(void* const* d_in, const int* in_sizes, int n_in,
                              void* d_out, int out_size, void* d_ws, size_t ws_size,
                              hipStream_t stream) {
  const float* x    = (const float*)d_in[0];
  const float* adj1 = (const float*)d_in[1];
  const float* adj2 = (const float*)d_in[2];
  const float* W1   = (const float*)d_in[3];
  const float* b1   = (const float*)d_in[4];
  const float* W2   = (const float*)d_in[5];
  const float* b2   = (const float*)d_in[6];
  const float* aw   = (const float*)d_in[7];
  const float* cl   = (const float*)d_in[8];
  float* out = (float*)d_out;

  // workspace layout
  char* ws = (char*)d_ws;
  unsigned short* Yt1 = (unsigned short*)(ws + 0);        // 64*10240*2 = 1310720
  unsigned short* Yt2 = (unsigned short*)(ws + 1310720);
  unsigned short* Wt1 = (unsigned short*)(ws + 2621440);  // 64*512*2 = 65536
  unsigned short* Wt2 = (unsigned short*)(ws + 2686976);
  float* Ep           = (float*)(ws + 2752512);           // partials start here

  const size_t fixed = 2752512;
  const size_t per_split = 2ull * NROWS * NHID * 4ull;    // both branches: 5.12 MB
  const bool static_ok = ws_size >= fixed + (size_t)NSPLIT * per_split;

  // zero Yt (covers the K-tail zero pad rows 10000..10239)
  hipMemsetAsync(Yt1, 0, 2 * 1310720, stream);
  prep_w<<<dim3(128), dim3(256), 0, stream>>>(W1, W2, Wt1, Wt2);
  gemm_xw<<<dim3(157), dim3(256), 0, stream>>>(x, Wt1, Wt2, Yt1, Yt2);

  if (static_ok) {
    gemm_adj<<<dim3(157, NSPLIT, 2), dim3(256), 0, stream>>>(adj1, adj2, Yt1, Yt2, Ep);
    fuse<<<dim3(2500), dim3(256), 0, stream>>>(Ep, NSPLIT, b1, b2, aw, cl, out);
  } else {
    int nsplit = 1;
    if (ws_size > fixed + per_split) {
      size_t s = (ws_size - fixed) / per_split;
      nsplit = (int)(s < 8 ? s : 8);
      if (nsplit < 1) nsplit = 1;
    }
    const int chunk = (KB_PAD + nsplit - 1) / nsplit;
    gemm_adj_dyn<<<dim3(157, nsplit, 2), dim3(256), 0, stream>>>(adj1, adj2, Yt1, Yt2,
                                                                 Ep, nsplit, chunk);
    fuse<<<dim3(2500), dim3(256), 0, stream>>>(Ep, nsplit, b1, b2, aw, cl, out);
  }
}

// Round 4
// 258.840 us; speedup vs baseline: 2.0785x; 1.4190x over previous
//
#include <hip/hip_runtime.h>
#include <math.h>

#define NROWS 10000
#define FEAT  512
#define NHID  64
#define NCLS  10
#define YT_STRIDE 10240   // 10000 padded (zeros in pad)
#define KB_PAD 320        // padded K blocks of 32
#define NSPLIT 8
#define CHUNK 40          // KB_PAD / NSPLIT

typedef __attribute__((ext_vector_type(8))) short short8;
typedef __attribute__((ext_vector_type(4))) float f32x4;

__device__ __forceinline__ short f2bf(float f) {
  union { float f; unsigned u; } v; v.f = f;
  unsigned r = v.u + 0x7fffu + ((v.u >> 16) & 1u);
  return (short)(r >> 16);
}

__device__ __forceinline__ float wsum64(float v) {
#pragma unroll
  for (int off = 32; off > 0; off >>= 1) v += __shfl_xor(v, off, 64);
  return v;
}

// async global->LDS, 16B per lane, LDS dest = wave-uniform base + lane*16
__device__ __forceinline__ void gload16(const void* g, void* l) {
  __builtin_amdgcn_global_load_lds(
      (const __attribute__((address_space(1))) unsigned int*)g,
      (__attribute__((address_space(3))) unsigned int*)l, 16, 0, 0);
}

// ---------------------------------------------------------------------------
__global__ __launch_bounds__(256) void prep_w(const float* __restrict__ W1,
                                              const float* __restrict__ W2,
                                              unsigned short* __restrict__ Wt1,
                                              unsigned short* __restrict__ Wt2) {
  int i = blockIdx.x * 256 + threadIdx.x;
  if (i >= FEAT * NHID) return;
  int k = i >> 6, h = i & 63;
  Wt1[h * FEAT + k] = (unsigned short)f2bf(W1[i]);
  Wt2[h * FEAT + k] = (unsigned short)f2bf(W2[i]);
}

// ---------------------------------------------------------------------------
// Kernel 1: Yt_b[col][row] = bf16((x @ W_b)[row][col]).  Flat wave-jobs:
// 625 row-tiles x 2 branches = 1250 independent waves (was 628 -> latency).
__global__ __launch_bounds__(256) void gemm_xw(const float* __restrict__ x,
                                               const unsigned short* __restrict__ Wt1,
                                               const unsigned short* __restrict__ Wt2,
                                               unsigned short* __restrict__ Yt1,
                                               unsigned short* __restrict__ Yt2) {
  const int lane = threadIdx.x & 63;
  const int wave = threadIdx.x >> 6;
  const int job = blockIdx.x * 4 + wave;
  if (job >= 1250) return;                 // no barriers in kernel: safe
  const int br = (job >= 625) ? 1 : 0;
  const int tile = job - 625 * br;
  const unsigned short* Wt = br ? Wt2 : Wt1;
  unsigned short* Yt       = br ? Yt2 : Yt1;
  const int rowbase = tile * 16;
  const int r16 = lane & 15, g = lane >> 4, ga = g * 8;

  const float* arow = x + (size_t)(rowbase + r16) * FEAT + ga;
  const unsigned short* bp = Wt + (size_t)r16 * FEAT + ga;

  f32x4 acc[4];
#pragma unroll
  for (int t = 0; t < 4; ++t) acc[t] = (f32x4){0.f, 0.f, 0.f, 0.f};

#pragma unroll
  for (int kb = 0; kb < FEAT / 32; ++kb) {
    const int k0 = kb * 32;
    const f32x4* ap = (const f32x4*)(arow + k0);
    f32x4 a0 = ap[0], a1 = ap[1];
    short8 af;
    af[0] = f2bf(a0[0]); af[1] = f2bf(a0[1]); af[2] = f2bf(a0[2]); af[3] = f2bf(a0[3]);
    af[4] = f2bf(a1[0]); af[5] = f2bf(a1[1]); af[6] = f2bf(a1[2]); af[7] = f2bf(a1[3]);
#pragma unroll
    for (int t = 0; t < 4; ++t) {
      short8 bf = *(const short8*)(bp + (size_t)t * 16 * FEAT + k0);
      acc[t] = __builtin_amdgcn_mfma_f32_16x16x32_bf16(af, bf, acc[t], 0, 0, 0);
    }
  }
#pragma unroll
  for (int t = 0; t < 4; ++t)
#pragma unroll
    for (int rr = 0; rr < 4; ++rr)
      Yt[(size_t)(t * 16 + r16) * YT_STRIDE + (rowbase + g * 4 + rr)] =
          (unsigned short)f2bf(acc[t][rr]);
}

// ---------------------------------------------------------------------------
// Kernel 2: E = adj @ Y.  LDS ring (D=4) staged entirely via global_load_lds;
// the ONLY vmem waits are inline-asm counted vmcnt (compiler emits none).
// Per iter per wave: 3 stage instrs (2 A + 1 B), 6 ds_read_b128, 4 MFMA.
// Source-swizzled layouts: A 4-way-conflict reads, B 2-way (free).
__global__ __launch_bounds__(256, 3) void gemm_adj(const float* __restrict__ adj1,
                                                   const float* __restrict__ adj2,
                                                   const unsigned short* __restrict__ Yt1,
                                                   const unsigned short* __restrict__ Yt2,
                                                   float* __restrict__ Ep) {
  __shared__ __attribute__((aligned(16))) float          Asm[4][2048]; // 4 x 8KB
  __shared__ __attribute__((aligned(16))) unsigned short Bsm[4][2048]; // 4 x 4KB

  const int sp = blockIdx.y;
  const int br = blockIdx.z;
  const float* adj         = br ? adj2 : adj1;
  const unsigned short* Yt = br ? Yt2 : Yt1;
  float* E = Ep + (size_t)(br * NSPLIT + sp) * NROWS * NHID;
  const int kb0 = sp * CHUNK;
  const int blockrow = blockIdx.x * 64;

  const int lane = threadIdx.x & 63;
  const int wave = threadIdx.x >> 6;

  // ---- staging source/dest precompute (per lane) ----
  // A tile layout byte(row, v) = row*128 + v*16, where v = (g^(row&3))*2 + h,
  // k = g*8 + h*4.  Chunk ai covers rows ai*8..ai*8+7, dest = ai*1024+lane*16.
  const int l8 = lane >> 3, v = lane & 7;
  const int arow0 = wave * 16 + l8;        // ai = 2*wave
  const int arow1 = wave * 16 + 8 + l8;    // ai = 2*wave+1
  const int g0 = (v >> 1) ^ (arow0 & 3), g1 = (v >> 1) ^ (arow1 & 3);
  const int akoff0 = g0 * 8 + (v & 1) * 4;
  const int akoff1 = g1 * 8 + (v & 1) * 4;
  const float* abase0 = adj + (size_t)min(blockrow + arow0, NROWS - 1) * NROWS;
  const float* abase1 = adj + (size_t)min(blockrow + arow1, NROWS - 1) * NROWS;
  const int adst0 = (wave * 2 + 0) * 256 + lane * 4;   // float index
  const int adst1 = (wave * 2 + 1) * 256 + lane * 4;
  // B tile layout byte(c, u) = c*64 + u*16, u = j ^ ((c>>1)&3), k = j*8.
  // Chunk w covers cols w*16..w*16+15, dest = w*1024 + lane*16.
  const int bj = (lane & 3) ^ (l8 & 3);
  const unsigned short* bbase =
      Yt + (size_t)(wave * 16 + (lane >> 2)) * YT_STRIDE + bj * 8;
  const int bdst = wave * 512 + lane * 8;              // ushort index

  // ---- read-side indices ----
  const int r16 = lane & 15, g = lane >> 4;
  const int ard  = (wave * 16 + r16) * 32 + ((g ^ (r16 & 3)) * 8);       // floats
  const int bsw  = (g ^ ((r16 >> 1) & 3)) * 8;                           // ushorts
  const int brd0 = (0 * 16 + r16) * 32 + bsw;
  const int brd1 = (1 * 16 + r16) * 32 + bsw;
  const int brd2 = (2 * 16 + r16) * 32 + bsw;
  const int brd3 = (3 * 16 + r16) * 32 + bsw;

  f32x4 acc0 = (f32x4){0.f, 0.f, 0.f, 0.f};
  f32x4 acc1 = acc0, acc2 = acc0, acc3 = acc0;

#define STAGE(T) { const int k0s = (kb0 + (T)) * 32; const int sl = (T) & 3;      \
    gload16(abase0 + min(k0s + akoff0, NROWS - 4), &Asm[sl][adst0]);              \
    gload16(abase1 + min(k0s + akoff1, NROWS - 4), &Asm[sl][adst1]);              \
    gload16(bbase + k0s, &Bsm[sl][bdst]); }

#define RC(T) { const int sl = (T) & 3;                                           \
    const f32x4* ap = (const f32x4*)&Asm[sl][ard];                                \
    f32x4 a0 = ap[0], a1 = ap[1];                                                 \
    short8 bf0 = *(const short8*)&Bsm[sl][brd0];                                  \
    short8 bf1 = *(const short8*)&Bsm[sl][brd1];                                  \
    short8 bf2 = *(const short8*)&Bsm[sl][brd2];                                  \
    short8 bf3 = *(const short8*)&Bsm[sl][brd3];                                  \
    short8 af;                                                                    \
    af[0] = f2bf(a0[0]); af[1] = f2bf(a0[1]); af[2] = f2bf(a0[2]); af[3] = f2bf(a0[3]); \
    af[4] = f2bf(a1[0]); af[5] = f2bf(a1[1]); af[6] = f2bf(a1[2]); af[7] = f2bf(a1[3]); \
    acc0 = __builtin_amdgcn_mfma_f32_16x16x32_bf16(af, bf0, acc0, 0, 0, 0);       \
    acc1 = __builtin_amdgcn_mfma_f32_16x16x32_bf16(af, bf1, acc1, 0, 0, 0);       \
    acc2 = __builtin_amdgcn_mfma_f32_16x16x32_bf16(af, bf2, acc2, 0, 0, 0);       \
    acc3 = __builtin_amdgcn_mfma_f32_16x16x32_bf16(af, bf3, acc3, 0, 0, 0); }

  STAGE(0) STAGE(1) STAGE(2) STAGE(3)

#pragma unroll 4
  for (int t = 0; t < CHUNK - 3; ++t) {
    asm volatile("s_waitcnt vmcnt(9)" ::: "memory");   // tile t resident (3*(D-1))
    __builtin_amdgcn_sched_barrier(0);
    __builtin_amdgcn_s_barrier();                      // all waves' stages visible
    RC(t)
    __builtin_amdgcn_s_barrier();                      // all waves done with slot
    if (t < CHUNK - 4) STAGE(t + 4)
  }
  asm volatile("s_waitcnt vmcnt(6)" ::: "memory");
  __builtin_amdgcn_sched_barrier(0);
  __builtin_amdgcn_s_barrier();
  RC(CHUNK - 3)
  asm volatile("s_waitcnt vmcnt(3)" ::: "memory");
  __builtin_amdgcn_sched_barrier(0);
  __builtin_amdgcn_s_barrier();
  RC(CHUNK - 2)
  asm volatile("s_waitcnt vmcnt(0)" ::: "memory");
  __builtin_amdgcn_sched_barrier(0);
  __builtin_amdgcn_s_barrier();
  RC(CHUNK - 1)
#undef STAGE
#undef RC

  // C layout: out-col = t*16 + r16, out-row = blockrow + wave*16 + g*4 + rr
#pragma unroll
  for (int rr = 0; rr < 4; ++rr) {
    const int grow = blockrow + wave * 16 + g * 4 + rr;
    if (grow < NROWS) {
      float* e = E + (size_t)grow * NHID + r16;
      e[0]  = acc0[rr];
      e[16] = acc1[rr];
      e[32] = acc2[rr];
      e[48] = acc3[rr];
    }
  }
}

// ---------------------------------------------------------------------------
// Fallback (dynamic split) if workspace is tight.
__global__ __launch_bounds__(256) void gemm_adj_dyn(const float* __restrict__ adj1,
                                                    const float* __restrict__ adj2,
                                                    const unsigned short* __restrict__ Yt1,
                                                    const unsigned short* __restrict__ Yt2,
                                                    float* __restrict__ Ep,
                                                    int nsplit, int chunk) {
  const int sp = blockIdx.y;
  const int br = blockIdx.z;
  const float* adj          = br ? adj2 : adj1;
  const unsigned short* Yt  = br ? Yt2 : Yt1;
  float* E = Ep + (size_t)(br * nsplit + sp) * NROWS * NHID;

  const int kb_begin = sp * chunk;
  const int kb_end   = min(kb_begin + chunk, KB_PAD);

  const int lane = threadIdx.x & 63;
  const int wave = threadIdx.x >> 6;
  const int rowbase = blockIdx.x * 64 + wave * 16;
  if (rowbase >= NROWS) return;
  const int r = lane & 15;
  const int g = lane >> 4;
  const int ga = g * 8;

  const float* arow = adj + (size_t)(rowbase + r) * NROWS;
  const size_t boff = (size_t)r * YT_STRIDE + ga;

  f32x4 acc0 = (f32x4){0.f, 0.f, 0.f, 0.f};
  f32x4 acc1 = acc0, acc2 = acc0, acc3 = acc0;

#pragma unroll 4
  for (int kb = kb_begin; kb < kb_end; ++kb) {
    const int k0 = kb * 32;
    const int kc = min(k0 + ga, 9992);
    const f32x4* ap = (const f32x4*)(arow + kc);
    f32x4 a0 = ap[0], a1 = ap[1];
    short8 af;
    af[0] = f2bf(a0[0]); af[1] = f2bf(a0[1]); af[2] = f2bf(a0[2]); af[3] = f2bf(a0[3]);
    af[4] = f2bf(a1[0]); af[5] = f2bf(a1[1]); af[6] = f2bf(a1[2]); af[7] = f2bf(a1[3]);
    short8 bf0 = *(const short8*)(Yt + boff + k0);
    short8 bf1 = *(const short8*)(Yt + boff + 16 * YT_STRIDE + k0);
    short8 bf2 = *(const short8*)(Yt + boff + 32 * YT_STRIDE + k0);
    short8 bf3 = *(const short8*)(Yt + boff + 48 * YT_STRIDE + k0);
    acc0 = __builtin_amdgcn_mfma_f32_16x16x32_bf16(af, bf0, acc0, 0, 0, 0);
    acc1 = __builtin_amdgcn_mfma_f32_16x16x32_bf16(af, bf1, acc1, 0, 0, 0);
    acc2 = __builtin_amdgcn_mfma_f32_16x16x32_bf16(af, bf2, acc2, 0, 0, 0);
    acc3 = __builtin_amdgcn_mfma_f32_16x16x32_bf16(af, bf3, acc3, 0, 0, 0);
  }

  const size_t ebase = (size_t)(rowbase + g * 4) * NHID + r;
#pragma unroll
  for (int rr = 0; rr < 4; ++rr) {
    E[ebase + (size_t)rr * NHID +  0] = acc0[rr];
    E[ebase + (size_t)rr * NHID + 16] = acc1[rr];
    E[ebase + (size_t)rr * NHID + 32] = acc2[rr];
    E[ebase + (size_t)rr * NHID + 48] = acc3[rr];
  }
}

// ---------------------------------------------------------------------------
// Kernel 3: split-K reduction + bias + attention fusion + DEC assignment.
__global__ __launch_bounds__(256) void fuse(const float* __restrict__ Ep,
                                            int nsplit,
                                            const float* __restrict__ b1,
                                            const float* __restrict__ b2,
                                            const float* __restrict__ aw,
                                            const float* __restrict__ cl,
                                            float* __restrict__ out) {
  const int lane = threadIdx.x & 63;
  const int wave = threadIdx.x >> 6;
  const int row = blockIdx.x * 4 + wave;
  if (row >= NROWS) return;

  const size_t off = (size_t)row * NHID + lane;
  const size_t bstride = (size_t)nsplit * NROWS * NHID;
  float e1 = b1[lane], e2 = b2[lane];
  for (int s = 0; s < nsplit; ++s) {
    e1 += Ep[(size_t)s * NROWS * NHID + off];
    e2 += Ep[bstride + (size_t)s * NROWS * NHID + off];
  }

  float a = aw[lane];
  float w1 = wsum64(e1 * a);
  float w2 = wsum64(e2 * a);
  float m = fmaxf(w1, w2);
  float x1 = expf(w1 - m), x2 = expf(w2 - m);
  float inv = 1.0f / (x1 + x2);
  float emb = (x1 * e1 + x2 * e2) * inv;
  out[off] = emb;

  // q_i ~ (1 + d2/alpha)^(-0.72); the *0.5 cancels in normalization
  float myq = 0.f, qs = 0.f;
#pragma unroll
  for (int c = 0; c < NCLS; ++c) {
    float d = emb - cl[c * NHID + lane];
    float s = wsum64(d * d);
    float t = exp2f(-0.72f * log2f(fmaf(5.0f, s, 1.0f)));
    qs += t;
    if (lane == c) myq = t;
  }
  if (lane < NCLS) out[(size_t)NROWS * NHID + (size_t)row * NCLS + lane] = myq / qs;
}

// ---------------------------------------------------------------------------
extern "C" void kernel_launch(void* const* d_in, const int* in_sizes, int n_in,
                              void* d_out, int out_size, void* d_ws, size_t ws_size,
                              hipStream_t stream) {
  const float* x    = (const float*)d_in[0];
  const float* adj1 = (const float*)d_in[1];
  const float* adj2 = (const float*)d_in[2];
  const float* W1   = (const float*)d_in[3];
  const float* b1   = (const float*)d_in[4];
  const float* W2   = (const float*)d_in[5];
  const float* b2   = (const float*)d_in[6];
  const float* aw   = (const float*)d_in[7];
  const float* cl   = (const float*)d_in[8];
  float* out = (float*)d_out;

  char* ws = (char*)d_ws;
  unsigned short* Yt1 = (unsigned short*)(ws + 0);        // 64*10240*2 = 1310720
  unsigned short* Yt2 = (unsigned short*)(ws + 1310720);
  unsigned short* Wt1 = (unsigned short*)(ws + 2621440);  // 64*512*2 = 65536
  unsigned short* Wt2 = (unsigned short*)(ws + 2686976);
  float* Ep           = (float*)(ws + 2752512);

  const size_t fixed = 2752512;
  const size_t per_split = 2ull * NROWS * NHID * 4ull;    // both branches: 5.12 MB
  const bool static_ok = ws_size >= fixed + (size_t)NSPLIT * per_split;

  hipMemsetAsync(Yt1, 0, 2 * 1310720, stream);
  prep_w<<<dim3(128), dim3(256), 0, stream>>>(W1, W2, Wt1, Wt2);
  gemm_xw<<<dim3(313), dim3(256), 0, stream>>>(x, Wt1, Wt2, Yt1, Yt2);

  if (static_ok) {
    gemm_adj<<<dim3(157, NSPLIT, 2), dim3(256), 0, stream>>>(adj1, adj2, Yt1, Yt2, Ep);
    fuse<<<dim3(2500), dim3(256), 0, stream>>>(Ep, NSPLIT, b1, b2, aw, cl, out);
  } else {
    int nsplit = 1;
    if (ws_size > fixed + per_split) {
      size_t s = (ws_size - fixed) / per_split;
      nsplit = (int)(s < 8 ? s : 8);
      if (nsplit < 1) nsplit = 1;
    }
    const int chunk = (KB_PAD + nsplit - 1) / nsplit;
    gemm_adj_dyn<<<dim3(157, nsplit, 2), dim3(256), 0, stream>>>(adj1, adj2, Yt1, Yt2,
                                                                 Ep, nsplit, chunk);
    fuse<<<dim3(2500), dim3(256), 0, stream>>>(Ep, nsplit, b1, b2, aw, cl, out);
  }
}